// Round 9
// baseline (336.886 us; speedup 1.0000x reference)
//
#include <hip/hip_runtime.h>

// GCN: agg-before-GEMM on both layers (A(hW) = (Ah)W).
//   es  = bf16( dinv[i] * emb[x[i]] )               (N x 32, 3.2 MB, L2-resident)
//   a1  = dinv[i] * (es[i] + sum_{e:dst=i} es[src]) (gather, fp32 accum)
//   hs  = bf16( dinv[i] * relu(a1 @ W1 + b1) )      stored as 4 slabs [q][N][32]
//   a2  = dinv[i] * (hs[i] + sum hs[src])           4 column passes, slab q L2-resident
//   out = a2 @ W2 + b2
// CSR build: bucket -> chunked-LDS-histogram counting sort (no global atomics).
// R8: k_agg128 was fabric-bound (FETCH 154MB, 12.8MB table vs 4MB/XCD L2) ->
// slab layout + 4 sequential passes keeps each 3.2MB slab resident per XCD;
// csr streamed with nontemporal loads so it can't evict the slab.

#define NPP   6250     // nodes per partition (N=50000 / 8)
#define NC    32       // chunks per partition

static inline int cdiv(int a, int b){ return (a + b - 1) / b; }

__device__ __forceinline__ unsigned short f2bf(float f){
    unsigned int u = __float_as_uint(f);
    u += 0x7fffu + ((u >> 16) & 1u);          // round-to-nearest-even
    return (unsigned short)(u >> 16);
}
__device__ __forceinline__ float bf2f(unsigned short b){
    return __uint_as_float(((unsigned int)b) << 16);
}

__global__ void k_zero_i32(int* __restrict__ p, int n){
    int i = blockIdx.x * blockDim.x + threadIdx.x;
    if (i < n) p[i] = 0;
}

// Bucket edges by dst-range into 8 staged partition arrays (LDS tiles,
// per-block coalesced flush; ~2k global atomics total on gcur).
__global__ __launch_bounds__(256) void k_bucket(const int* __restrict__ src,
        const int* __restrict__ dst, int E, int* __restrict__ staged_s,
        int* __restrict__ staged_d, int* __restrict__ gcur, int npp, int C){
    __shared__ int  qcnt[8];
    __shared__ int  qbase[8];
    __shared__ int2 qbuf[8 * 256];   // 16 KB
    int tid = threadIdx.x;
    if (tid < 8) qcnt[tid] = 0;
    __syncthreads();
    int e0 = blockIdx.x * 1024 + tid * 4;
    if (e0 + 3 < E){
        int4 d4 = *(const int4*)(dst + e0);
        int4 s4 = *(const int4*)(src + e0);
        int dd[4] = {d4.x, d4.y, d4.z, d4.w};
        int ss[4] = {s4.x, s4.y, s4.z, s4.w};
        #pragma unroll
        for (int i = 0; i < 4; i++){
            int p = dd[i] / npp;
            int pos = atomicAdd(&qcnt[p], 1);
            if (pos < 256) qbuf[p * 256 + pos] = make_int2(ss[i], dd[i]);
            else {          // statistically unreachable overflow fallback
                int gp = atomicAdd(&gcur[p], 1);
                staged_s[(size_t)p * C + gp] = ss[i];
                staged_d[(size_t)p * C + gp] = dd[i];
            }
        }
    } else {
        for (int e = e0; e < E && e < e0 + 4; e++){
            int d = dst[e], s = src[e];
            int p = d / npp;
            int pos = atomicAdd(&qcnt[p], 1);
            if (pos < 256) qbuf[p * 256 + pos] = make_int2(s, d);
            else {
                int gp = atomicAdd(&gcur[p], 1);
                staged_s[(size_t)p * C + gp] = s;
                staged_d[(size_t)p * C + gp] = d;
            }
        }
    }
    __syncthreads();
    if (tid < 8){
        int nq = min(qcnt[tid], 256);
        qbase[tid] = (nq > 0) ? atomicAdd(&gcur[tid], nq) : 0;
    }
    __syncthreads();
    for (int b = 0; b < 8; b++){
        int nq = min(qcnt[b], 256);
        int gb = qbase[b];
        for (int i = tid; i < nq; i += 256){
            int2 pr = qbuf[b * 256 + i];
            staged_s[(size_t)b * C + gb + i] = pr.x;
            staged_d[(size_t)b * C + gb + i] = pr.y;
        }
    }
}

// Per-(partition,chunk) dst histogram via LDS atomics -> H[p][c][0..npp).
__global__ __launch_bounds__(256) void k_hist(const int* __restrict__ staged_d,
        const int* __restrict__ gcur, int C, int CH, int npp, int* __restrict__ H){
    __shared__ int hist[NPP];
    int part  = blockIdx.x & 7;
    int chunk = blockIdx.x >> 3;
    int tid = threadIdx.x;
    for (int i = tid; i < npp; i += 256) hist[i] = 0;
    __syncthreads();
    int pc = gcur[part];
    int lo = part * npp;
    int e0 = chunk * CH, e1 = min(e0 + CH, pc);
    const int* sd = staged_d + (size_t)part * C;
    for (int e = e0 + tid; e < e1; e += 256)
        atomicAdd(&hist[sd[e] - lo], 1);
    __syncthreads();
    int* Hrow = H + (size_t)(part * NC + chunk) * npp;
    for (int i = tid; i < npp; i += 256) Hrow[i] = hist[i];
}

// Per-node serial prefix over the NC chunk histograms: H becomes per-chunk
// exclusive base rank; ecount = total; dinv fused; per-block sums -> bsum.
__global__ __launch_bounds__(256) void k_nodescan(int* __restrict__ H, int npp, int n,
        int* __restrict__ ecount, float* __restrict__ dinv, int* __restrict__ bsum){
    __shared__ int s[256];
    int t = blockIdx.x * 256 + threadIdx.x;   // t == node id (partitions contiguous)
    int run = 0;
    if (t < 8 * npp && t < n){
        int p  = t / npp;
        int dl = t - p * npp;
        #pragma unroll
        for (int c = 0; c < NC; c++){
            size_t idx = (size_t)(p * NC + c) * npp + dl;
            int v = H[idx];
            H[idx] = run;
            run += v;
        }
        ecount[t] = run;
        dinv[t] = rsqrtf((float)run + 1.0f);   // +1 self-loop
    }
    s[threadIdx.x] = run;
    __syncthreads();
    for (int d = 128; d > 0; d >>= 1){
        if (threadIdx.x < d) s[threadIdx.x] += s[threadIdx.x + d];
        __syncthreads();
    }
    if (threadIdx.x == 0) bsum[blockIdx.x] = s[0];
}

// Fused scanB+scanC: every block re-scans the nb block sums in LDS (nb<=256),
// then does its 256-element Hillis-Steele scan -> offsets.
__global__ __launch_bounds__(256) void k_scanBC(const int* __restrict__ ecount, int n,
        const int* __restrict__ bsum, int nb, int* __restrict__ offsets){
    __shared__ int bs[256];
    __shared__ int s[256];
    int t = threadIdx.x;
    bs[t] = (t < nb) ? bsum[t] : 0;
    __syncthreads();
    if (t == 0){
        int run = 0;
        for (int b = 0; b < nb; b++){ int v = bs[b]; bs[b] = run; run += v; }
    }
    __syncthreads();
    int i = blockIdx.x * 256 + t;
    int v = (i < n) ? ecount[i] : 0;
    s[t] = v;
    __syncthreads();
    for (int d = 1; d < 256; d <<= 1){
        int x = (t >= d) ? s[t - d] : 0;
        __syncthreads();
        s[t] += x;
        __syncthreads();
    }
    if (i < n) offsets[i] = bs[blockIdx.x] + s[t] - v;
}

// Fill csr via LDS cursor preloaded with chunk base ranks. No global atomics.
__global__ __launch_bounds__(256) void k_fill3(const int* __restrict__ staged_s,
        const int* __restrict__ staged_d, const int* __restrict__ gcur, int C, int CH,
        int npp, const int* __restrict__ H, const int* __restrict__ offsets,
        int* __restrict__ csr_src){
    __shared__ int cur[NPP];
    int part  = blockIdx.x & 7;
    int chunk = blockIdx.x >> 3;
    int tid = threadIdx.x;
    const int* Hrow = H + (size_t)(part * NC + chunk) * npp;
    for (int i = tid; i < npp; i += 256) cur[i] = Hrow[i];
    __syncthreads();
    int pc = gcur[part];
    int lo = part * npp;
    int e0 = chunk * CH, e1 = min(e0 + CH, pc);
    const int* ss = staged_s + (size_t)part * C;
    const int* sd = staged_d + (size_t)part * C;
    for (int e = e0 + tid; e < e1; e += 256){
        int d = sd[e];
        int r = atomicAdd(&cur[d - lo], 1);
        csr_src[offsets[d] + r] = ss[e];
    }
}

// es[i][c] = bf16( emb[x[i]][c] * dinv[i] )
__global__ void k_scale(const float* __restrict__ emb, const int* __restrict__ x,
                        const float* __restrict__ dinv, unsigned short* __restrict__ es, int n){
    int idx = blockIdx.x * blockDim.x + threadIdx.x;
    if (idx >= n * 32) return;
    int i = idx >> 5;
    int c = idx & 31;
    es[idx] = f2bf(emb[(size_t)x[i] * 32 + c] * dinv[i]);
}

// a1[i] = dinv[i] * (es[i] + sum es[src]) ; 32 lanes/node, bf16 loads, unroll 8.
// csr via nontemporal loads: the 6.4MB csr stream must not evict the 3.2MB es table.
__global__ __launch_bounds__(256) void k_agg32(const unsigned short* __restrict__ es,
        const int* __restrict__ offsets, const int* __restrict__ ecount,
        const int* __restrict__ csr, const float* __restrict__ dinv,
        float* __restrict__ a1, int n){
    int node = blockIdx.x * 8 + (threadIdx.x >> 5);
    int lane = threadIdx.x & 31;
    if (node >= n) return;
    int off = offsets[node], cnt = ecount[node];
    float s0 = bf2f(es[(size_t)node * 32 + lane]);   // self-loop term
    float s1 = 0.f;
    int e = 0;
    for (; e + 8 <= cnt; e += 8){
        int i0 = __builtin_nontemporal_load(csr + off + e + 0);
        int i1 = __builtin_nontemporal_load(csr + off + e + 1);
        int i2 = __builtin_nontemporal_load(csr + off + e + 2);
        int i3 = __builtin_nontemporal_load(csr + off + e + 3);
        int i4 = __builtin_nontemporal_load(csr + off + e + 4);
        int i5 = __builtin_nontemporal_load(csr + off + e + 5);
        int i6 = __builtin_nontemporal_load(csr + off + e + 6);
        int i7 = __builtin_nontemporal_load(csr + off + e + 7);
        unsigned short v0 = es[(size_t)i0 * 32 + lane];
        unsigned short v1 = es[(size_t)i1 * 32 + lane];
        unsigned short v2 = es[(size_t)i2 * 32 + lane];
        unsigned short v3 = es[(size_t)i3 * 32 + lane];
        unsigned short v4 = es[(size_t)i4 * 32 + lane];
        unsigned short v5 = es[(size_t)i5 * 32 + lane];
        unsigned short v6 = es[(size_t)i6 * 32 + lane];
        unsigned short v7 = es[(size_t)i7 * 32 + lane];
        s0 += bf2f(v0) + bf2f(v2) + bf2f(v4) + bf2f(v6);
        s1 += bf2f(v1) + bf2f(v3) + bf2f(v5) + bf2f(v7);
    }
    for (; e < cnt; e++) s0 += bf2f(es[(size_t)csr[off + e] * 32 + lane]);
    a1[(size_t)node * 32 + lane] = dinv[node] * (s0 + s1);
}

// hs slab layout: hs[q][row][c32], q = col/32. mlp1 writes slabs.
__global__ __launch_bounds__(256) void k_mlp1(const float* __restrict__ a1,
        const float* __restrict__ W1, const float* __restrict__ b1,
        const float* __restrict__ dinv, unsigned short* __restrict__ hs, int n){
    __shared__ float w[32 * 128];
    for (int i = threadIdx.x; i < 32 * 128; i += 256) w[i] = W1[i];
    __syncthreads();
    int c4  = (threadIdx.x & 31) * 4;
    int row = blockIdx.x * 8 + (threadIdx.x >> 5);
    if (row >= n) return;
    const float4* ar = (const float4*)(a1 + (size_t)row * 32);
    float4 acc = *(const float4*)(b1 + c4);
    #pragma unroll
    for (int k4 = 0; k4 < 8; k4++){
        float4 av = ar[k4];
        float4 w0 = *(const float4*)&w[(k4 * 4 + 0) * 128 + c4];
        float4 w1 = *(const float4*)&w[(k4 * 4 + 1) * 128 + c4];
        float4 w2 = *(const float4*)&w[(k4 * 4 + 2) * 128 + c4];
        float4 w3 = *(const float4*)&w[(k4 * 4 + 3) * 128 + c4];
        acc.x += av.x * w0.x + av.y * w1.x + av.z * w2.x + av.w * w3.x;
        acc.y += av.x * w0.y + av.y * w1.y + av.z * w2.y + av.w * w3.y;
        acc.z += av.x * w0.z + av.y * w1.z + av.z * w2.z + av.w * w3.z;
        acc.w += av.x * w0.w + av.y * w1.w + av.z * w2.w + av.w * w3.w;
    }
    float dv = dinv[row];
    ushort4 o;
    o.x = f2bf(dv * fmaxf(acc.x, 0.f));
    o.y = f2bf(dv * fmaxf(acc.y, 0.f));
    o.z = f2bf(dv * fmaxf(acc.z, 0.f));
    o.w = f2bf(dv * fmaxf(acc.w, 0.f));
    int q   = c4 >> 5;
    int c32 = c4 & 31;
    *(ushort4*)(hs + (size_t)q * n * 32 + (size_t)row * 32 + c32) = o;
}

// Layer-2 aggregation, one column pass: gather slab q (3.2 MB, L2-resident).
// 8 lanes/node x ushort4 = 64 B/row = 1 line/edge/pass. csr nontemporal.
__global__ __launch_bounds__(256) void k_agg128q(const unsigned short* __restrict__ slab,
        const int* __restrict__ offsets, const int* __restrict__ ecount,
        const int* __restrict__ csr, const float* __restrict__ dinv,
        float* __restrict__ a2, int n, int cb){
    int node = blockIdx.x * 32 + (threadIdx.x >> 3);
    int l4 = (threadIdx.x & 7) * 4;   // col within slab
    if (node >= n) return;
    int off = offsets[node], cnt = ecount[node];
    ushort4 sv = *(const ushort4*)(slab + (size_t)node * 32 + l4);   // self-loop
    float ax0 = bf2f(sv.x), ax1 = 0.f;
    float ay0 = bf2f(sv.y), ay1 = 0.f;
    float az0 = bf2f(sv.z), az1 = 0.f;
    float aw0 = bf2f(sv.w), aw1 = 0.f;
    int e = 0;
    for (; e + 8 <= cnt; e += 8){
        int i0 = __builtin_nontemporal_load(csr + off + e + 0);
        int i1 = __builtin_nontemporal_load(csr + off + e + 1);
        int i2 = __builtin_nontemporal_load(csr + off + e + 2);
        int i3 = __builtin_nontemporal_load(csr + off + e + 3);
        int i4 = __builtin_nontemporal_load(csr + off + e + 4);
        int i5 = __builtin_nontemporal_load(csr + off + e + 5);
        int i6 = __builtin_nontemporal_load(csr + off + e + 6);
        int i7 = __builtin_nontemporal_load(csr + off + e + 7);
        ushort4 v0 = *(const ushort4*)(slab + (size_t)i0 * 32 + l4);
        ushort4 v1 = *(const ushort4*)(slab + (size_t)i1 * 32 + l4);
        ushort4 v2 = *(const ushort4*)(slab + (size_t)i2 * 32 + l4);
        ushort4 v3 = *(const ushort4*)(slab + (size_t)i3 * 32 + l4);
        ushort4 v4 = *(const ushort4*)(slab + (size_t)i4 * 32 + l4);
        ushort4 v5 = *(const ushort4*)(slab + (size_t)i5 * 32 + l4);
        ushort4 v6 = *(const ushort4*)(slab + (size_t)i6 * 32 + l4);
        ushort4 v7 = *(const ushort4*)(slab + (size_t)i7 * 32 + l4);
        ax0 += bf2f(v0.x) + bf2f(v2.x) + bf2f(v4.x) + bf2f(v6.x);
        ax1 += bf2f(v1.x) + bf2f(v3.x) + bf2f(v5.x) + bf2f(v7.x);
        ay0 += bf2f(v0.y) + bf2f(v2.y) + bf2f(v4.y) + bf2f(v6.y);
        ay1 += bf2f(v1.y) + bf2f(v3.y) + bf2f(v5.y) + bf2f(v7.y);
        az0 += bf2f(v0.z) + bf2f(v2.z) + bf2f(v4.z) + bf2f(v6.z);
        az1 += bf2f(v1.z) + bf2f(v3.z) + bf2f(v5.z) + bf2f(v7.z);
        aw0 += bf2f(v0.w) + bf2f(v2.w) + bf2f(v4.w) + bf2f(v6.w);
        aw1 += bf2f(v1.w) + bf2f(v3.w) + bf2f(v5.w) + bf2f(v7.w);
    }
    for (; e < cnt; e++){
        ushort4 v = *(const ushort4*)(slab + (size_t)csr[off + e] * 32 + l4);
        ax0 += bf2f(v.x); ay0 += bf2f(v.y); az0 += bf2f(v.z); aw0 += bf2f(v.w);
    }
    float dv = dinv[node];
    float4 r;
    r.x = dv * (ax0 + ax1); r.y = dv * (ay0 + ay1);
    r.z = dv * (az0 + az1); r.w = dv * (aw0 + aw1);
    *(float4*)(a2 + (size_t)node * 128 + cb + l4) = r;
}

// out = a2 @ W2 + b2. 64 rows x 64 cols per block (32 KB LDS half of W2),
// thread = 4 rows x 4 cols. Grid = cdiv(n,64)*2 -> ~5 resident blocks/CU.
#define MLP2_STEP(KK, COMP) {                                        \
    float4 wv = *(const float4*)&w[(k + KK) * 64 + c4];              \
    acc0.x += a0.COMP * wv.x; acc0.y += a0.COMP * wv.y;              \
    acc0.z += a0.COMP * wv.z; acc0.w += a0.COMP * wv.w;              \
    acc1.x += a1v.COMP * wv.x; acc1.y += a1v.COMP * wv.y;            \
    acc1.z += a1v.COMP * wv.z; acc1.w += a1v.COMP * wv.w;            \
    acc2.x += a2v.COMP * wv.x; acc2.y += a2v.COMP * wv.y;            \
    acc2.z += a2v.COMP * wv.z; acc2.w += a2v.COMP * wv.w;            \
    acc3.x += a3v.COMP * wv.x; acc3.y += a3v.COMP * wv.y;            \
    acc3.z += a3v.COMP * wv.z; acc3.w += a3v.COMP * wv.w; }

__global__ __launch_bounds__(256) void k_mlp2(const float* __restrict__ a2,
        const float* __restrict__ W2, const float* __restrict__ b2,
        float* __restrict__ out, int n){
    __shared__ float w[128 * 64];   // 32 KB: cols [cbase, cbase+64)
    int half  = blockIdx.x & 1;
    int rb    = blockIdx.x >> 1;
    int cbase = half * 64;
    for (int i = threadIdx.x; i < 128 * 16; i += 256){
        int k = i >> 4, c = (i & 15) * 4;
        *(float4*)&w[k * 64 + c] = *(const float4*)(W2 + (size_t)k * 128 + cbase + c);
    }
    __syncthreads();
    int c4 = (threadIdx.x & 15) * 4;            // 16 col-threads x 4 cols
    int r0 = rb * 64 + (threadIdx.x >> 4) * 4;  // 16 row-threads x 4 rows
    float4 bias = *(const float4*)(b2 + cbase + c4);
    float4 acc0 = bias, acc1 = bias, acc2 = bias, acc3 = bias;
    const float* h0 = a2 + (size_t)min(r0 + 0, n - 1) * 128;
    const float* h1 = a2 + (size_t)min(r0 + 1, n - 1) * 128;
    const float* h2 = a2 + (size_t)min(r0 + 2, n - 1) * 128;
    const float* h3 = a2 + (size_t)min(r0 + 3, n - 1) * 128;
    for (int k = 0; k < 128; k += 4){
        float4 a0  = *(const float4*)(h0 + k);
        float4 a1v = *(const float4*)(h1 + k);
        float4 a2v = *(const float4*)(h2 + k);
        float4 a3v = *(const float4*)(h3 + k);
        MLP2_STEP(0, x)
        MLP2_STEP(1, y)
        MLP2_STEP(2, z)
        MLP2_STEP(3, w)
    }
    if (r0 + 0 < n) *(float4*)(out + (size_t)(r0 + 0) * 128 + cbase + c4) = acc0;
    if (r0 + 1 < n) *(float4*)(out + (size_t)(r0 + 1) * 128 + cbase + c4) = acc1;
    if (r0 + 2 < n) *(float4*)(out + (size_t)(r0 + 2) * 128 + cbase + c4) = acc2;
    if (r0 + 3 < n) *(float4*)(out + (size_t)(r0 + 3) * 128 + cbase + c4) = acc3;
}

extern "C" void kernel_launch(void* const* d_in, const int* in_sizes, int n_in,
                              void* d_out, int out_size, void* d_ws, size_t ws_size,
                              hipStream_t stream){
    const int*   x    = (const int*)d_in[0];
    const int*   ei   = (const int*)d_in[1];
    const float* emb  = (const float*)d_in[2];
    const float* W1   = (const float*)d_in[3];
    const float* b1   = (const float*)d_in[4];
    const float* W2   = (const float*)d_in[5];
    const float* b2   = (const float*)d_in[6];
    const int N = in_sizes[0];
    const int E = in_sizes[1] / 2;
    const int* srcv = ei;
    const int* dstv = ei + E;
    float* out = (float*)d_out;

    char* p = (char*)d_ws;
    auto alloc = [&](size_t bytes) -> char* {
        char* r = p; p += (bytes + 255) & ~(size_t)255; return r;
    };
    int nb = cdiv(N, 256);
    int*            ecount  = (int*)           alloc((size_t)(N + 8) * 4); // +8: gcur
    int*            gcur    = ecount + N;
    int*            offsets = (int*)           alloc((size_t)N * 4);
    int*            bsum    = (int*)           alloc((size_t)nb * 4);
    float*          dinv    = (float*)         alloc((size_t)N * 4);
    int*            csr     = (int*)           alloc((size_t)E * 4);
    unsigned short* es      = (unsigned short*)alloc((size_t)N * 32 * 2);
    float*          a1      = (float*)         alloc((size_t)N * 32 * 4);
    unsigned short* hs      = (unsigned short*)alloc((size_t)N * 128 * 2); // 4 slabs [q][N][32]
    float*          a2      = (float*)         alloc((size_t)N * 128 * 4);
    (void)ws_size; (void)n_in; (void)out_size;

    const int npp = cdiv(N, 8);          // nodes per partition (== NPP for N=50000)
    const int C   = E / 8 + 65536;       // staged capacity per partition
    const int CH  = cdiv(C, NC);         // edges per chunk
    // staging aliases a2 (17 MB <= 25.6 MB); dead before k_agg128q writes a2.
    int* staged_s = (int*)a2;
    int* staged_d = staged_s + (size_t)8 * C;
    // H aliases es+a1 (6.4 MB <= 9.6 MB); dead before k_scale writes es.
    int* H = (int*)es;

    // --- CSR build (no global atomics on hot path) ---
    k_zero_i32<<<1, 64, 0, stream>>>(gcur, 8);
    k_bucket  <<<cdiv(E, 1024), 256, 0, stream>>>(srcv, dstv, E, staged_s, staged_d, gcur, npp, C);
    k_hist    <<<8 * NC, 256, 0, stream>>>(staged_d, gcur, C, CH, npp, H);
    k_nodescan<<<nb, 256, 0, stream>>>(H, npp, N, ecount, dinv, bsum);
    k_scanBC  <<<nb, 256, 0, stream>>>(ecount, N, bsum, nb, offsets);
    k_fill3   <<<8 * NC, 256, 0, stream>>>(staged_s, staged_d, gcur, C, CH, npp, H, offsets, csr);

    // --- layer 1: scale -> agg(32) -> GEMM+relu (+dinv pre-scale for layer 2) ---
    k_scale <<<cdiv(N * 32, 256), 256, 0, stream>>>(emb, x, dinv, es, N);
    k_agg32 <<<cdiv(N, 8), 256, 0, stream>>>(es, offsets, ecount, csr, dinv, a1, N);
    k_mlp1  <<<cdiv(N, 8), 256, 0, stream>>>(a1, W1, b1, dinv, hs, N);

    // --- layer 2: 4 column passes (slab q L2-resident) -> GEMM+bias -> out ---
    for (int q = 0; q < 4; q++){
        k_agg128q<<<cdiv(N, 32), 256, 0, stream>>>(hs + (size_t)q * N * 32,
                offsets, ecount, csr, dinv, a2, N, q * 32);
    }
    k_mlp2  <<<cdiv(N, 64) * 2, 256, 0, stream>>>(a2, W2, b2, out, N);
}

// Round 10
// 273.652 us; speedup vs baseline: 1.2311x; 1.2311x over previous
//
#include <hip/hip_runtime.h>

// GCN: agg-before-GEMM on both layers (A(hW) = (Ah)W).
//   es  = bf16( dinv[i] * emb[x[i]] )               (N x 32, 3.2 MB, L2-resident)
//   L1 fused: a1(LDS) = dinv*(es[i]+sum es[src]);  hs = bf16(dinv*relu(a1@W1+b1))
//   L2 fused: a2(LDS) = dinv*(hs[i]+sum hs[src]);  out = a2@W2 + b2
// CSR build: bucket -> chunked-LDS-histogram counting sort (no global atomics).
// R9 post-mortem: 4-pass slab gather REGRESSED (4x index loads/loop iters/launches
// swamped the ~50MB traffic saving) -> reverted to single-pass [N][128] gather.
// R10: fuse agg+GEMM per layer; kills a1 (12.8MB) and a2 (51MB) round-trips.

#define NPP   6250     // nodes per partition (N=50000 / 8)
#define NC    32       // chunks per partition

static inline int cdiv(int a, int b){ return (a + b - 1) / b; }

__device__ __forceinline__ unsigned short f2bf(float f){
    unsigned int u = __float_as_uint(f);
    u += 0x7fffu + ((u >> 16) & 1u);          // round-to-nearest-even
    return (unsigned short)(u >> 16);
}
__device__ __forceinline__ float bf2f(unsigned short b){
    return __uint_as_float(((unsigned int)b) << 16);
}

__global__ void k_zero_i32(int* __restrict__ p, int n){
    int i = blockIdx.x * blockDim.x + threadIdx.x;
    if (i < n) p[i] = 0;
}

// Bucket edges by dst-range into 8 staged partition arrays (LDS tiles,
// per-block coalesced flush; ~2k global atomics total on gcur).
__global__ __launch_bounds__(256) void k_bucket(const int* __restrict__ src,
        const int* __restrict__ dst, int E, int* __restrict__ staged_s,
        int* __restrict__ staged_d, int* __restrict__ gcur, int npp, int C){
    __shared__ int  qcnt[8];
    __shared__ int  qbase[8];
    __shared__ int2 qbuf[8 * 256];   // 16 KB
    int tid = threadIdx.x;
    if (tid < 8) qcnt[tid] = 0;
    __syncthreads();
    int e0 = blockIdx.x * 1024 + tid * 4;
    if (e0 + 3 < E){
        int4 d4 = *(const int4*)(dst + e0);
        int4 s4 = *(const int4*)(src + e0);
        int dd[4] = {d4.x, d4.y, d4.z, d4.w};
        int ss[4] = {s4.x, s4.y, s4.z, s4.w};
        #pragma unroll
        for (int i = 0; i < 4; i++){
            int p = dd[i] / npp;
            int pos = atomicAdd(&qcnt[p], 1);
            if (pos < 256) qbuf[p * 256 + pos] = make_int2(ss[i], dd[i]);
            else {          // statistically unreachable overflow fallback
                int gp = atomicAdd(&gcur[p], 1);
                staged_s[(size_t)p * C + gp] = ss[i];
                staged_d[(size_t)p * C + gp] = dd[i];
            }
        }
    } else {
        for (int e = e0; e < E && e < e0 + 4; e++){
            int d = dst[e], s = src[e];
            int p = d / npp;
            int pos = atomicAdd(&qcnt[p], 1);
            if (pos < 256) qbuf[p * 256 + pos] = make_int2(s, d);
            else {
                int gp = atomicAdd(&gcur[p], 1);
                staged_s[(size_t)p * C + gp] = s;
                staged_d[(size_t)p * C + gp] = d;
            }
        }
    }
    __syncthreads();
    if (tid < 8){
        int nq = min(qcnt[tid], 256);
        qbase[tid] = (nq > 0) ? atomicAdd(&gcur[tid], nq) : 0;
    }
    __syncthreads();
    for (int b = 0; b < 8; b++){
        int nq = min(qcnt[b], 256);
        int gb = qbase[b];
        for (int i = tid; i < nq; i += 256){
            int2 pr = qbuf[b * 256 + i];
            staged_s[(size_t)b * C + gb + i] = pr.x;
            staged_d[(size_t)b * C + gb + i] = pr.y;
        }
    }
}

// Per-(partition,chunk) dst histogram via LDS atomics -> H[p][c][0..npp).
__global__ __launch_bounds__(256) void k_hist(const int* __restrict__ staged_d,
        const int* __restrict__ gcur, int C, int CH, int npp, int* __restrict__ H){
    __shared__ int hist[NPP];
    int part  = blockIdx.x & 7;
    int chunk = blockIdx.x >> 3;
    int tid = threadIdx.x;
    for (int i = tid; i < npp; i += 256) hist[i] = 0;
    __syncthreads();
    int pc = gcur[part];
    int lo = part * npp;
    int e0 = chunk * CH, e1 = min(e0 + CH, pc);
    const int* sd = staged_d + (size_t)part * C;
    for (int e = e0 + tid; e < e1; e += 256)
        atomicAdd(&hist[sd[e] - lo], 1);
    __syncthreads();
    int* Hrow = H + (size_t)(part * NC + chunk) * npp;
    for (int i = tid; i < npp; i += 256) Hrow[i] = hist[i];
}

// Per-node serial prefix over the NC chunk histograms: H becomes per-chunk
// exclusive base rank; ecount = total; dinv fused; per-block sums -> bsum.
__global__ __launch_bounds__(256) void k_nodescan(int* __restrict__ H, int npp, int n,
        int* __restrict__ ecount, float* __restrict__ dinv, int* __restrict__ bsum){
    __shared__ int s[256];
    int t = blockIdx.x * 256 + threadIdx.x;   // t == node id (partitions contiguous)
    int run = 0;
    if (t < 8 * npp && t < n){
        int p  = t / npp;
        int dl = t - p * npp;
        #pragma unroll
        for (int c = 0; c < NC; c++){
            size_t idx = (size_t)(p * NC + c) * npp + dl;
            int v = H[idx];
            H[idx] = run;
            run += v;
        }
        ecount[t] = run;
        dinv[t] = rsqrtf((float)run + 1.0f);   // +1 self-loop
    }
    s[threadIdx.x] = run;
    __syncthreads();
    for (int d = 128; d > 0; d >>= 1){
        if (threadIdx.x < d) s[threadIdx.x] += s[threadIdx.x + d];
        __syncthreads();
    }
    if (threadIdx.x == 0) bsum[blockIdx.x] = s[0];
}

// Fused scanB+scanC: every block re-scans the nb block sums in LDS (nb<=256),
// then does its 256-element Hillis-Steele scan -> offsets.
__global__ __launch_bounds__(256) void k_scanBC(const int* __restrict__ ecount, int n,
        const int* __restrict__ bsum, int nb, int* __restrict__ offsets){
    __shared__ int bs[256];
    __shared__ int s[256];
    int t = threadIdx.x;
    bs[t] = (t < nb) ? bsum[t] : 0;
    __syncthreads();
    if (t == 0){
        int run = 0;
        for (int b = 0; b < nb; b++){ int v = bs[b]; bs[b] = run; run += v; }
    }
    __syncthreads();
    int i = blockIdx.x * 256 + t;
    int v = (i < n) ? ecount[i] : 0;
    s[t] = v;
    __syncthreads();
    for (int d = 1; d < 256; d <<= 1){
        int x = (t >= d) ? s[t - d] : 0;
        __syncthreads();
        s[t] += x;
        __syncthreads();
    }
    if (i < n) offsets[i] = bs[blockIdx.x] + s[t] - v;
}

// Fill csr via LDS cursor preloaded with chunk base ranks. No global atomics.
__global__ __launch_bounds__(256) void k_fill3(const int* __restrict__ staged_s,
        const int* __restrict__ staged_d, const int* __restrict__ gcur, int C, int CH,
        int npp, const int* __restrict__ H, const int* __restrict__ offsets,
        int* __restrict__ csr_src){
    __shared__ int cur[NPP];
    int part  = blockIdx.x & 7;
    int chunk = blockIdx.x >> 3;
    int tid = threadIdx.x;
    const int* Hrow = H + (size_t)(part * NC + chunk) * npp;
    for (int i = tid; i < npp; i += 256) cur[i] = Hrow[i];
    __syncthreads();
    int pc = gcur[part];
    int lo = part * npp;
    int e0 = chunk * CH, e1 = min(e0 + CH, pc);
    const int* ss = staged_s + (size_t)part * C;
    const int* sd = staged_d + (size_t)part * C;
    for (int e = e0 + tid; e < e1; e += 256){
        int d = sd[e];
        int r = atomicAdd(&cur[d - lo], 1);
        csr_src[offsets[d] + r] = ss[e];
    }
}

// es[i][c] = bf16( emb[x[i]][c] * dinv[i] )
__global__ void k_scale(const float* __restrict__ emb, const int* __restrict__ x,
                        const float* __restrict__ dinv, unsigned short* __restrict__ es, int n){
    int idx = blockIdx.x * blockDim.x + threadIdx.x;
    if (idx >= n * 32) return;
    int i = idx >> 5;
    int c = idx & 31;
    es[idx] = f2bf(emb[(size_t)x[i] * 32 + c] * dinv[i]);
}

// Layer 1 fused: gather(32-dim, es L2-resident) -> LDS a1 tile -> GEMM W1 -> hs.
// 8 nodes/block; phase A: 32 lanes/node, bf16 loads, unroll 8; phase B: 128 cols.
__global__ __launch_bounds__(256) void k_l1(const unsigned short* __restrict__ es,
        const int* __restrict__ offsets, const int* __restrict__ ecount,
        const int* __restrict__ csr, const float* __restrict__ dinv,
        const float* __restrict__ W1, const float* __restrict__ b1,
        unsigned short* __restrict__ hs, int n){
    __shared__ float w[32 * 128];     // 16 KB
    __shared__ float a1t[8][32];      // 1 KB
    for (int i = threadIdx.x; i < 32 * 128; i += 256) w[i] = W1[i];
    int g    = threadIdx.x >> 5;
    int lane = threadIdx.x & 31;
    int node = blockIdx.x * 8 + g;
    // --- phase A: aggregate into LDS ---
    if (node < n){
        int off = offsets[node], cnt = ecount[node];
        float s0 = bf2f(es[(size_t)node * 32 + lane]);   // self-loop term
        float s1 = 0.f;
        int e = 0;
        for (; e + 8 <= cnt; e += 8){
            int i0 = csr[off + e + 0], i1 = csr[off + e + 1];
            int i2 = csr[off + e + 2], i3 = csr[off + e + 3];
            int i4 = csr[off + e + 4], i5 = csr[off + e + 5];
            int i6 = csr[off + e + 6], i7 = csr[off + e + 7];
            unsigned short v0 = es[(size_t)i0 * 32 + lane];
            unsigned short v1 = es[(size_t)i1 * 32 + lane];
            unsigned short v2 = es[(size_t)i2 * 32 + lane];
            unsigned short v3 = es[(size_t)i3 * 32 + lane];
            unsigned short v4 = es[(size_t)i4 * 32 + lane];
            unsigned short v5 = es[(size_t)i5 * 32 + lane];
            unsigned short v6 = es[(size_t)i6 * 32 + lane];
            unsigned short v7 = es[(size_t)i7 * 32 + lane];
            s0 += bf2f(v0) + bf2f(v2) + bf2f(v4) + bf2f(v6);
            s1 += bf2f(v1) + bf2f(v3) + bf2f(v5) + bf2f(v7);
        }
        for (; e < cnt; e++) s0 += bf2f(es[(size_t)csr[off + e] * 32 + lane]);
        a1t[g][lane] = dinv[node] * (s0 + s1);
    }
    __syncthreads();
    // --- phase B: hs[node] = bf16(dinv * relu(a1 @ W1 + b1)) ---
    if (node >= n) return;
    int c4 = lane * 4;
    float4 acc = *(const float4*)(b1 + c4);
    #pragma unroll
    for (int k4 = 0; k4 < 8; k4++){
        float4 av = *(const float4*)&a1t[g][k4 * 4];
        float4 w0 = *(const float4*)&w[(k4 * 4 + 0) * 128 + c4];
        float4 w1 = *(const float4*)&w[(k4 * 4 + 1) * 128 + c4];
        float4 w2 = *(const float4*)&w[(k4 * 4 + 2) * 128 + c4];
        float4 w3 = *(const float4*)&w[(k4 * 4 + 3) * 128 + c4];
        acc.x += av.x * w0.x + av.y * w1.x + av.z * w2.x + av.w * w3.x;
        acc.y += av.x * w0.y + av.y * w1.y + av.z * w2.y + av.w * w3.y;
        acc.z += av.x * w0.z + av.y * w1.z + av.z * w2.z + av.w * w3.z;
        acc.w += av.x * w0.w + av.y * w1.w + av.z * w2.w + av.w * w3.w;
    }
    float dv = dinv[node];
    ushort4 o;
    o.x = f2bf(dv * fmaxf(acc.x, 0.f));
    o.y = f2bf(dv * fmaxf(acc.y, 0.f));
    o.z = f2bf(dv * fmaxf(acc.z, 0.f));
    o.w = f2bf(dv * fmaxf(acc.w, 0.f));
    *(ushort4*)(hs + (size_t)node * 128 + c4) = o;
}

// Layer 2 fused: gather(128-dim hs) -> LDS a2 tile (16 KB) -> GEMM W2 -> out.
// 32 nodes/block; phase A: 8 groups x 32 lanes, 4 nodes/group, ushort4, unroll 8;
// phase B: thread = 4 rows x 4 cols, W2 from global (64 KB, L1/L2-resident).
__global__ __launch_bounds__(256) void k_l2(const unsigned short* __restrict__ hs,
        const int* __restrict__ offsets, const int* __restrict__ ecount,
        const int* __restrict__ csr, const float* __restrict__ dinv,
        const float* __restrict__ W2, const float* __restrict__ b2,
        float* __restrict__ out, int n){
    __shared__ float a2t[32 * 128];   // 16 KB
    int g    = threadIdx.x >> 5;
    int lane = threadIdx.x & 31;
    int c4g  = lane * 4;
    // --- phase A: aggregate 4 nodes per 32-lane group ---
    #pragma unroll
    for (int j = 0; j < 4; j++){
        int nl = g + 8 * j;
        int node = blockIdx.x * 32 + nl;
        if (node < n){
            int off = offsets[node], cnt = ecount[node];
            ushort4 sv = *(const ushort4*)(hs + (size_t)node * 128 + c4g);
            float ax0 = bf2f(sv.x), ax1 = 0.f;
            float ay0 = bf2f(sv.y), ay1 = 0.f;
            float az0 = bf2f(sv.z), az1 = 0.f;
            float aw0 = bf2f(sv.w), aw1 = 0.f;
            int e = 0;
            for (; e + 8 <= cnt; e += 8){
                int i0 = csr[off + e + 0], i1 = csr[off + e + 1];
                int i2 = csr[off + e + 2], i3 = csr[off + e + 3];
                int i4 = csr[off + e + 4], i5 = csr[off + e + 5];
                int i6 = csr[off + e + 6], i7 = csr[off + e + 7];
                ushort4 v0 = *(const ushort4*)(hs + (size_t)i0 * 128 + c4g);
                ushort4 v1 = *(const ushort4*)(hs + (size_t)i1 * 128 + c4g);
                ushort4 v2 = *(const ushort4*)(hs + (size_t)i2 * 128 + c4g);
                ushort4 v3 = *(const ushort4*)(hs + (size_t)i3 * 128 + c4g);
                ushort4 v4 = *(const ushort4*)(hs + (size_t)i4 * 128 + c4g);
                ushort4 v5 = *(const ushort4*)(hs + (size_t)i5 * 128 + c4g);
                ushort4 v6 = *(const ushort4*)(hs + (size_t)i6 * 128 + c4g);
                ushort4 v7 = *(const ushort4*)(hs + (size_t)i7 * 128 + c4g);
                ax0 += bf2f(v0.x) + bf2f(v2.x) + bf2f(v4.x) + bf2f(v6.x);
                ax1 += bf2f(v1.x) + bf2f(v3.x) + bf2f(v5.x) + bf2f(v7.x);
                ay0 += bf2f(v0.y) + bf2f(v2.y) + bf2f(v4.y) + bf2f(v6.y);
                ay1 += bf2f(v1.y) + bf2f(v3.y) + bf2f(v5.y) + bf2f(v7.y);
                az0 += bf2f(v0.z) + bf2f(v2.z) + bf2f(v4.z) + bf2f(v6.z);
                az1 += bf2f(v1.z) + bf2f(v3.z) + bf2f(v5.z) + bf2f(v7.z);
                aw0 += bf2f(v0.w) + bf2f(v2.w) + bf2f(v4.w) + bf2f(v6.w);
                aw1 += bf2f(v1.w) + bf2f(v3.w) + bf2f(v5.w) + bf2f(v7.w);
            }
            for (; e < cnt; e++){
                ushort4 v = *(const ushort4*)(hs + (size_t)csr[off + e] * 128 + c4g);
                ax0 += bf2f(v.x); ay0 += bf2f(v.y); az0 += bf2f(v.z); aw0 += bf2f(v.w);
            }
            float dv = dinv[node];
            float4 r;
            r.x = dv * (ax0 + ax1); r.y = dv * (ay0 + ay1);
            r.z = dv * (az0 + az1); r.w = dv * (aw0 + aw1);
            *(float4*)&a2t[nl * 128 + c4g] = r;
        }
    }
    __syncthreads();
    // --- phase B: out[rows] = a2t[rows] @ W2 + b2 ; 4 rows x 4 cols/thread ---
    int c4 = lane * 4;                 // output col base
    int r0 = (threadIdx.x >> 5) * 4;   // 4 local rows
    float4 bias = *(const float4*)(b2 + c4);
    float4 acc0 = bias, acc1 = bias, acc2 = bias, acc3 = bias;
    for (int k = 0; k < 128; k += 4){
        float4 a0  = *(const float4*)&a2t[(r0 + 0) * 128 + k];
        float4 a1v = *(const float4*)&a2t[(r0 + 1) * 128 + k];
        float4 a2v = *(const float4*)&a2t[(r0 + 2) * 128 + k];
        float4 a3v = *(const float4*)&a2t[(r0 + 3) * 128 + k];
        #pragma unroll
        for (int kk = 0; kk < 4; kk++){
            float4 wv = *(const float4*)(W2 + (size_t)(k + kk) * 128 + c4);
            float b0 = (kk == 0) ? a0.x  : (kk == 1) ? a0.y  : (kk == 2) ? a0.z  : a0.w;
            float b1v= (kk == 0) ? a1v.x : (kk == 1) ? a1v.y : (kk == 2) ? a1v.z : a1v.w;
            float b2v= (kk == 0) ? a2v.x : (kk == 1) ? a2v.y : (kk == 2) ? a2v.z : a2v.w;
            float b3 = (kk == 0) ? a3v.x : (kk == 1) ? a3v.y : (kk == 2) ? a3v.z : a3v.w;
            acc0.x += b0 * wv.x; acc0.y += b0 * wv.y; acc0.z += b0 * wv.z; acc0.w += b0 * wv.w;
            acc1.x += b1v * wv.x; acc1.y += b1v * wv.y; acc1.z += b1v * wv.z; acc1.w += b1v * wv.w;
            acc2.x += b2v * wv.x; acc2.y += b2v * wv.y; acc2.z += b2v * wv.z; acc2.w += b2v * wv.w;
            acc3.x += b3 * wv.x; acc3.y += b3 * wv.y; acc3.z += b3 * wv.z; acc3.w += b3 * wv.w;
        }
    }
    int rb = blockIdx.x * 32 + r0;
    if (rb + 0 < n) *(float4*)(out + (size_t)(rb + 0) * 128 + c4) = acc0;
    if (rb + 1 < n) *(float4*)(out + (size_t)(rb + 1) * 128 + c4) = acc1;
    if (rb + 2 < n) *(float4*)(out + (size_t)(rb + 2) * 128 + c4) = acc2;
    if (rb + 3 < n) *(float4*)(out + (size_t)(rb + 3) * 128 + c4) = acc3;
}

extern "C" void kernel_launch(void* const* d_in, const int* in_sizes, int n_in,
                              void* d_out, int out_size, void* d_ws, size_t ws_size,
                              hipStream_t stream){
    const int*   x    = (const int*)d_in[0];
    const int*   ei   = (const int*)d_in[1];
    const float* emb  = (const float*)d_in[2];
    const float* W1   = (const float*)d_in[3];
    const float* b1   = (const float*)d_in[4];
    const float* W2   = (const float*)d_in[5];
    const float* b2   = (const float*)d_in[6];
    const int N = in_sizes[0];
    const int E = in_sizes[1] / 2;
    const int* srcv = ei;
    const int* dstv = ei + E;
    float* out = (float*)d_out;

    char* p = (char*)d_ws;
    auto alloc = [&](size_t bytes) -> char* {
        char* r = p; p += (bytes + 255) & ~(size_t)255; return r;
    };
    int nb = cdiv(N, 256);
    int*            ecount  = (int*)           alloc((size_t)(N + 8) * 4); // +8: gcur
    int*            gcur    = ecount + N;
    int*            offsets = (int*)           alloc((size_t)N * 4);
    int*            bsum    = (int*)           alloc((size_t)nb * 4);
    float*          dinv    = (float*)         alloc((size_t)N * 4);
    int*            csr     = (int*)           alloc((size_t)E * 4);
    unsigned short* es      = (unsigned short*)alloc((size_t)N * 32 * 2);
    int*            H       = (int*)           alloc((size_t)8 * NC * NPP * 4); // 6.4 MB
    unsigned short* hs      = (unsigned short*)alloc((size_t)N * 128 * 2);
    int*            staged  = (int*)           alloc((size_t)2 * (E + 8 * 65536) * 4);
    (void)ws_size; (void)n_in; (void)out_size;

    const int npp = cdiv(N, 8);          // nodes per partition (== NPP for N=50000)
    const int C   = E / 8 + 65536;       // staged capacity per partition
    const int CH  = cdiv(C, NC);         // edges per chunk
    int* staged_s = staged;
    int* staged_d = staged_s + (size_t)8 * C;

    // --- CSR build (no global atomics on hot path) ---
    k_zero_i32<<<1, 64, 0, stream>>>(gcur, 8);
    k_bucket  <<<cdiv(E, 1024), 256, 0, stream>>>(srcv, dstv, E, staged_s, staged_d, gcur, npp, C);
    k_hist    <<<8 * NC, 256, 0, stream>>>(staged_d, gcur, C, CH, npp, H);
    k_nodescan<<<nb, 256, 0, stream>>>(H, npp, N, ecount, dinv, bsum);
    k_scanBC  <<<nb, 256, 0, stream>>>(ecount, N, bsum, nb, offsets);
    k_fill3   <<<8 * NC, 256, 0, stream>>>(staged_s, staged_d, gcur, C, CH, npp, H, offsets, csr);

    // --- layer 1 (fused): scale -> [gather+GEMM] -> hs ---
    k_scale <<<cdiv(N * 32, 256), 256, 0, stream>>>(emb, x, dinv, es, N);
    k_l1    <<<cdiv(N, 8), 256, 0, stream>>>(es, offsets, ecount, csr, dinv, W1, b1, hs, N);

    // --- layer 2 (fused): [gather+GEMM] -> out ---
    k_l2    <<<cdiv(N, 32), 256, 0, stream>>>(hs, offsets, ecount, csr, dinv, W2, b2, out, N);
}